// Round 1
// baseline (287.070 us; speedup 1.0000x reference)
//
#include <hip/hip_runtime.h>
#include <math.h>

#define NHEAD 8
#define NPT 4
#define HDIM 32
#define IMG 64      // H = W = 64
#define CDIM 256
#define NQ 4096     // queries per batch
#define BATCH 8

// ---------------------------------------------------------------------------
// Guarded tiled f32 GEMM with bias:  C[m, n] = A[m, :K] @ B[:K, n] + bias[n]
// BM=64, BN=64, BK=16; 256 threads; each thread computes a 4x4 micro-tile.
// M must be a multiple of BM; K a multiple of BK; N guarded (per-float4).
// ---------------------------------------------------------------------------
template<int BM, int BN, int BK>
__global__ __launch_bounds__(256)
void gemm_bias_kernel(const float* __restrict__ A, int lda,
                      const float* __restrict__ B, int ldb,
                      const float* __restrict__ bias,
                      float* __restrict__ C, int ldc,
                      int N, int K)
{
    __shared__ float As[BK][BM];   // A tile, transposed (k-major)
    __shared__ float Bs[BK][BN];

    const int tid = threadIdx.x;
    const int gm = blockIdx.x * BM;
    const int gn = blockIdx.y * BN;
    const int tr = tid >> 4;    // 0..15 -> rows tr*4 .. tr*4+3
    const int tc = tid & 15;    // 0..15 -> cols tc*4 .. tc*4+3

    float acc[4][4];
    #pragma unroll
    for (int i = 0; i < 4; ++i)
        #pragma unroll
        for (int j = 0; j < 4; ++j) acc[i][j] = 0.f;

    for (int k0 = 0; k0 < K; k0 += BK) {
        // --- load A tile (BM x BK), store transposed ---
        {
            const int arow = tid >> 2;         // 0..63
            const int akk  = (tid & 3) << 2;   // 0,4,8,12
            float4 a4 = *(const float4*)(A + (size_t)(gm + arow) * lda + k0 + akk);
            As[akk + 0][arow] = a4.x;
            As[akk + 1][arow] = a4.y;
            As[akk + 2][arow] = a4.z;
            As[akk + 3][arow] = a4.w;
        }
        // --- load B tile (BK x BN) ---
        {
            const int bk = tid >> 4;           // 0..15
            const int bc = (tid & 15) << 2;    // 0..60
            float4 b4 = make_float4(0.f, 0.f, 0.f, 0.f);
            if (gn + bc < N)
                b4 = *(const float4*)(B + (size_t)(k0 + bk) * ldb + gn + bc);
            *(float4*)&Bs[bk][bc] = b4;
        }
        __syncthreads();

        #pragma unroll
        for (int k = 0; k < BK; ++k) {
            float4 av = *(const float4*)&As[k][tr << 2];
            float4 bv = *(const float4*)&Bs[k][tc << 2];
            float a_[4] = {av.x, av.y, av.z, av.w};
            float b_[4] = {bv.x, bv.y, bv.z, bv.w};
            #pragma unroll
            for (int i = 0; i < 4; ++i)
                #pragma unroll
                for (int j = 0; j < 4; ++j)
                    acc[i][j] = fmaf(a_[i], b_[j], acc[i][j]);
        }
        __syncthreads();
    }

    const int gc = gn + (tc << 2);
    if (gc < N) {
        float4 b4 = *(const float4*)(bias + gc);
        #pragma unroll
        for (int i = 0; i < 4; ++i) {
            const int row = gm + (tr << 2) + i;
            float4 o;
            o.x = acc[i][0] + b4.x;
            o.y = acc[i][1] + b4.y;
            o.z = acc[i][2] + b4.z;
            o.w = acc[i][3] + b4.w;
            *(float4*)(C + (size_t)row * ldc + gc) = o;
        }
    }
}

// ---------------------------------------------------------------------------
// Sampling kernel: one block per (b, n); 256 threads = 8 heads x 32 channels.
// lin:   [B*N, 96]  (cols 0..63 = offset logits h*8+p*2+{x,y}; 64..95 = attn
//        logits h*4+p)
// projv: [B, H*W, 256]  projected value, channel = h*32 + d
// out:   sampled [B*N, 256]
// ---------------------------------------------------------------------------
__global__ __launch_bounds__(256)
void sample_kernel(const float* __restrict__ projv,
                   const float* __restrict__ lin,
                   const float* __restrict__ refp,
                   float* __restrict__ sampled)
{
    const int bn = blockIdx.x;
    const int b = bn >> 12;            // NQ = 4096
    const int t = threadIdx.x;
    const int h = t >> 5;
    const int d = t & 31;

    __shared__ float s_lin[96];
    __shared__ float s_ref[2];
    if (t < 96) s_lin[t] = lin[(size_t)bn * 96 + t];
    if (t < 2)  s_ref[t] = refp[(size_t)bn * 2 + t];
    __syncthreads();

    // softmax over the 4 points for this head
    float lg[4];
    #pragma unroll
    for (int p = 0; p < 4; ++p) lg[p] = s_lin[64 + h * 4 + p];
    float mx = fmaxf(fmaxf(lg[0], lg[1]), fmaxf(lg[2], lg[3]));
    float ea[4];
    float esum = 0.f;
    #pragma unroll
    for (int p = 0; p < 4; ++p) { ea[p] = expf(lg[p] - mx); esum += ea[p]; }
    const float inv = 1.f / esum;

    const float* vbase = projv + (size_t)b * (NQ * CDIM) + h * HDIM + d;

    float acc = 0.f;
    #pragma unroll
    for (int p = 0; p < 4; ++p) {
        const float ox = tanhf(s_lin[h * 8 + p * 2 + 0]) * 0.5f;
        const float oy = tanhf(s_lin[h * 8 + p * 2 + 1]) * 0.5f;
        const float lx = fminf(fmaxf(s_ref[0] + ox, 0.f), 1.f);
        const float ly = fminf(fmaxf(s_ref[1] + oy, 0.f), 1.f);
        const float x = lx * (float)IMG - 0.5f;
        const float y = ly * (float)IMG - 0.5f;
        const float x0f = floorf(x), y0f = floorf(y);
        const int x0 = (int)x0f, y0 = (int)y0f;
        const float wx1 = x - x0f, wx0 = 1.f - wx1;
        const float wy1 = y - y0f, wy0 = 1.f - wy1;

        float v = 0.f;
        if (y0 >= 0) {
            const float* r0 = vbase + (size_t)(y0 * IMG) * CDIM;
            if (x0 >= 0)       v += wx0 * wy0 * r0[(size_t)x0 * CDIM];
            if (x0 + 1 < IMG)  v += wx1 * wy0 * r0[(size_t)(x0 + 1) * CDIM];
        }
        if (y0 + 1 < IMG) {
            const float* r1 = vbase + (size_t)((y0 + 1) * IMG) * CDIM;
            if (x0 >= 0)       v += wx0 * wy1 * r1[(size_t)x0 * CDIM];
            if (x0 + 1 < IMG)  v += wx1 * wy1 * r1[(size_t)(x0 + 1) * CDIM];
        }
        acc = fmaf(ea[p] * inv, v, acc);
    }
    sampled[(size_t)bn * CDIM + t] = acc;
}

// ---------------------------------------------------------------------------
extern "C" void kernel_launch(void* const* d_in, const int* in_sizes, int n_in,
                              void* d_out, int out_size, void* d_ws, size_t ws_size,
                              hipStream_t stream)
{
    const float* query  = (const float*)d_in[0];
    const float* value  = (const float*)d_in[1];
    const float* refp   = (const float*)d_in[2];
    const float* W_off  = (const float*)d_in[3];
    const float* b_off  = (const float*)d_in[4];
    const float* W_attn = (const float*)d_in[5];
    const float* b_attn = (const float*)d_in[6];
    const float* W_val  = (const float*)d_in[7];
    const float* b_val  = (const float*)d_in[8];
    const float* W_out  = (const float*)d_in[9];
    const float* b_out  = (const float*)d_in[10];
    float* out = (float*)d_out;

    const int M = BATCH * NQ;  // 32768

    // workspace layout (all f32):
    float* projv   = (float*)d_ws;                       // M * 256
    float* sampled = projv + (size_t)M * CDIM;           // M * 256
    float* lin     = sampled + (size_t)M * CDIM;         // M * 96

    dim3 blk(256);

    // 1) value projection: projv = value @ W_val + b_val     [32768 x 256 x 256]
    gemm_bias_kernel<64, 64, 16><<<dim3(M / 64, 4), blk, 0, stream>>>(
        value, CDIM, W_val, CDIM, b_val, projv, CDIM, CDIM, CDIM);

    // 2a) offset logits: lin[:, 0:64] = query @ W_off + b_off
    gemm_bias_kernel<64, 64, 16><<<dim3(M / 64, 1), blk, 0, stream>>>(
        query, CDIM, W_off, 64, b_off, lin, 96, 64, CDIM);

    // 2b) attn logits: lin[:, 64:96] = query @ W_attn + b_attn
    gemm_bias_kernel<64, 64, 16><<<dim3(M / 64, 1), blk, 0, stream>>>(
        query, CDIM, W_attn, 32, b_attn, lin + 64, 96, 32, CDIM);

    // 3) bilinear sampling + softmax-weighted accumulation
    sample_kernel<<<dim3(M), blk, 0, stream>>>(projv, lin, refp, sampled);

    // 4) output projection: out = sampled @ W_out + b_out
    gemm_bias_kernel<64, 64, 16><<<dim3(M / 64, 4), blk, 0, stream>>>(
        sampled, CDIM, W_out, CDIM, b_out, out, CDIM, CDIM, CDIM);
}

// Round 2
// 103.862 us; speedup vs baseline: 2.7640x; 2.7640x over previous
//
#include <hip/hip_runtime.h>
#include <math.h>

#define NHEAD 8
#define NPT 4
#define HDIM 32
#define IMG 64      // H = W = 64
#define CDIM 256
#define NQ 4096
#define BATCH 8
#define MTOT (BATCH * NQ)   // 32768

typedef __attribute__((ext_vector_type(8))) short bf16x8;
typedef __attribute__((ext_vector_type(4))) float f32x4;

__device__ __forceinline__ unsigned short f2b(float f) {
    union { float f; unsigned u; } v; v.f = f;
    unsigned r = (v.u + 0x7FFFu + ((v.u >> 16) & 1u)) >> 16;
    return (unsigned short)r;
}
__device__ __forceinline__ float b2f(unsigned short u) {
    union { unsigned u; float f; } v; v.u = ((unsigned)u) << 16;
    return v.f;
}

// ---------------------------------------------------------------------------
// f32 -> bf16 conversion of `value` (vectorized 8/thread)
// ---------------------------------------------------------------------------
__global__ __launch_bounds__(256)
void cvt_value_kernel(const float* __restrict__ in, unsigned short* __restrict__ out, int n8)
{
    int i = blockIdx.x * 256 + threadIdx.x;
    if (i >= n8) return;
    const float4 a = ((const float4*)in)[i * 2];
    const float4 b = ((const float4*)in)[i * 2 + 1];
    unsigned short us[8] = { f2b(a.x), f2b(a.y), f2b(a.z), f2b(a.w),
                             f2b(b.x), f2b(b.y), f2b(b.z), f2b(b.w) };
    ((uint4*)out)[i] = *(const uint4*)us;
}

// ---------------------------------------------------------------------------
// Weight prep: W_val^T and W_out^T in bf16 (Bt[n][k]); pack W_off|W_attn (f32)
// ---------------------------------------------------------------------------
__global__ __launch_bounds__(256)
void cvt_weights_kernel(const float* __restrict__ Wv, const float* __restrict__ Wo,
                        const float* __restrict__ Woff, const float* __restrict__ Wattn,
                        const float* __restrict__ boff, const float* __restrict__ battn,
                        unsigned short* __restrict__ Wv_t, unsigned short* __restrict__ Wo_t,
                        float* __restrict__ Wboth, float* __restrict__ bias_both)
{
    int tid = blockIdx.x * 256 + threadIdx.x;   // 0 .. 65535
    int n = tid & 255, k = tid >> 8;
    Wv_t[n * 256 + k] = f2b(Wv[k * 256 + n]);
    Wo_t[n * 256 + k] = f2b(Wo[k * 256 + n]);
    if (tid < 256 * 96) {
        int r = tid / 96, c = tid - r * 96;
        Wboth[tid] = (c < 64) ? Woff[r * 64 + c] : Wattn[r * 32 + (c - 64)];
    }
    if (tid < 96) bias_both[tid] = (tid < 64) ? boff[tid] : battn[tid - 64];
}

// ---------------------------------------------------------------------------
// Guarded tiled f32 GEMM with bias (for the offset/attn projection, N=96)
// ---------------------------------------------------------------------------
template<int BM, int BN, int BK>
__global__ __launch_bounds__(256)
void gemm_bias_kernel(const float* __restrict__ A, int lda,
                      const float* __restrict__ B, int ldb,
                      const float* __restrict__ bias,
                      float* __restrict__ C, int ldc,
                      int N, int K)
{
    __shared__ float As[BK][BM];
    __shared__ float Bs[BK][BN];

    const int tid = threadIdx.x;
    const int gm = blockIdx.x * BM;
    const int gn = blockIdx.y * BN;
    const int tr = tid >> 4;
    const int tc = tid & 15;

    float acc[4][4];
    #pragma unroll
    for (int i = 0; i < 4; ++i)
        #pragma unroll
        for (int j = 0; j < 4; ++j) acc[i][j] = 0.f;

    for (int k0 = 0; k0 < K; k0 += BK) {
        {
            const int arow = tid >> 2;
            const int akk  = (tid & 3) << 2;
            float4 a4 = *(const float4*)(A + (size_t)(gm + arow) * lda + k0 + akk);
            As[akk + 0][arow] = a4.x;
            As[akk + 1][arow] = a4.y;
            As[akk + 2][arow] = a4.z;
            As[akk + 3][arow] = a4.w;
        }
        {
            const int bk = tid >> 4;
            const int bc = (tid & 15) << 2;
            float4 b4 = make_float4(0.f, 0.f, 0.f, 0.f);
            if (gn + bc < N)
                b4 = *(const float4*)(B + (size_t)(k0 + bk) * ldb + gn + bc);
            *(float4*)&Bs[bk][bc] = b4;
        }
        __syncthreads();

        #pragma unroll
        for (int k = 0; k < BK; ++k) {
            float4 av = *(const float4*)&As[k][tr << 2];
            float4 bv = *(const float4*)&Bs[k][tc << 2];
            float a_[4] = {av.x, av.y, av.z, av.w};
            float b_[4] = {bv.x, bv.y, bv.z, bv.w};
            #pragma unroll
            for (int i = 0; i < 4; ++i)
                #pragma unroll
                for (int j = 0; j < 4; ++j)
                    acc[i][j] = fmaf(a_[i], b_[j], acc[i][j]);
        }
        __syncthreads();
    }

    const int gc = gn + (tc << 2);
    if (gc < N) {
        float4 b4 = *(const float4*)(bias + gc);
        #pragma unroll
        for (int i = 0; i < 4; ++i) {
            const int row = gm + (tr << 2) + i;
            float4 o;
            o.x = acc[i][0] + b4.x;
            o.y = acc[i][1] + b4.y;
            o.z = acc[i][2] + b4.z;
            o.w = acc[i][3] + b4.w;
            *(float4*)(C + (size_t)row * ldc + gc) = o;
        }
    }
}

// ---------------------------------------------------------------------------
// bf16 MFMA GEMM: C[M x 256] = A[M x 256](bf16) @ Bt^T + bias
//   Bt is [256][256] bf16 with Bt[n][k] = B[k][n]  (pre-transposed weights)
// 128x128 tile, BK=64, 4 waves, each wave 64x64 via 4x4 frags of 16x16x32.
// ---------------------------------------------------------------------------
template<bool OUT_BF16>
__global__ __launch_bounds__(256)
void gemm_bf16_kernel(const unsigned short* __restrict__ A,
                      const unsigned short* __restrict__ Bt,
                      const float* __restrict__ bias,
                      void* __restrict__ C)
{
    __shared__ unsigned short As[128][64];
    __shared__ unsigned short Bs[128][64];

    const int tid  = threadIdx.x;
    const int lane = tid & 63;
    const int wid  = tid >> 6;
    const int gm = blockIdx.x * 128;
    const int gn = blockIdx.y * 128;
    const int wr = (wid >> 1) * 64;
    const int wc = (wid & 1) * 64;

    f32x4 acc[4][4];
    #pragma unroll
    for (int m = 0; m < 4; ++m)
        #pragma unroll
        for (int n = 0; n < 4; ++n)
            #pragma unroll
            for (int r = 0; r < 4; ++r) acc[m][n][r] = 0.f;

    const int l15 = lane & 15;
    const int lk  = (lane >> 4) * 8;

    for (int k0 = 0; k0 < 256; k0 += 64) {
        #pragma unroll
        for (int it = 0; it < 4; ++it) {
            const int chunk = it * 256 + tid;      // 0..1023
            const int row = chunk >> 3;            // 0..127
            const int kc  = (chunk & 7) << 3;      // 0..56
            *(uint4*)&As[row][kc] = *(const uint4*)&A [(size_t)(gm + row) * 256 + k0 + kc];
            *(uint4*)&Bs[row][kc] = *(const uint4*)&Bt[(size_t)(gn + row) * 256 + k0 + kc];
        }
        __syncthreads();

        #pragma unroll
        for (int kk = 0; kk < 64; kk += 32) {
            bf16x8 a[4], b[4];
            #pragma unroll
            for (int m = 0; m < 4; ++m)
                a[m] = *(const bf16x8*)&As[wr + m * 16 + l15][kk + lk];
            #pragma unroll
            for (int n = 0; n < 4; ++n)
                b[n] = *(const bf16x8*)&Bs[wc + n * 16 + l15][kk + lk];
            #pragma unroll
            for (int m = 0; m < 4; ++m)
                #pragma unroll
                for (int n = 0; n < 4; ++n)
                    acc[m][n] = __builtin_amdgcn_mfma_f32_16x16x32_bf16(a[m], b[n], acc[m][n], 0, 0, 0);
        }
        __syncthreads();
    }

    const int cr = (lane >> 4) * 4;
    #pragma unroll
    for (int n = 0; n < 4; ++n) {
        const int col = gn + wc + n * 16 + l15;
        const float bv = bias[col];
        #pragma unroll
        for (int m = 0; m < 4; ++m) {
            #pragma unroll
            for (int r = 0; r < 4; ++r) {
                const int row = gm + wr + m * 16 + cr + r;
                const float v = acc[m][n][r] + bv;
                if (OUT_BF16)
                    ((unsigned short*)C)[(size_t)row * 256 + col] = f2b(v);
                else
                    ((float*)C)[(size_t)row * 256 + col] = v;
            }
        }
    }
}

// ---------------------------------------------------------------------------
// Fused sampling: block handles 2 queries. First 64 lanes compute per-(h,p)
// tanh offsets, bilinear corner weights (premultiplied by softmax attn) and
// packed clamped coords; then 256 threads gather (2 channels each, ushort2).
// ---------------------------------------------------------------------------
__global__ __launch_bounds__(256)
void sample_gather_kernel(const unsigned short* __restrict__ projv, // [B][4096][256] bf16
                          const float* __restrict__ lin,            // [M][96]
                          const float* __restrict__ refp,           // [M][2]
                          unsigned short* __restrict__ sampled)     // [M][256] bf16
{
    __shared__ float4 s_w[2][32];
    __shared__ unsigned s_xy[2][32];

    const int t = threadIdx.x;
    const int bn0 = blockIdx.x * 2;

    if (t < 64) {
        const int sub = t >> 5;
        const int q = t & 31;          // h*4 + p
        const int h = q >> 2;
        const int p = q & 3;
        const int bn = bn0 + sub;
        const float2 rp = *(const float2*)&refp[(size_t)bn * 2];
        const float2 ol = *(const float2*)&lin[(size_t)bn * 96 + h * 8 + p * 2];
        const float al  = lin[(size_t)bn * 96 + 64 + q];

        float mx = al;
        mx = fmaxf(mx, __shfl_xor(mx, 1));
        mx = fmaxf(mx, __shfl_xor(mx, 2));
        float e = expf(al - mx);
        float s = e;
        s += __shfl_xor(s, 1);
        s += __shfl_xor(s, 2);
        const float aw = e / s;

        const float lx = fminf(fmaxf(rp.x + tanhf(ol.x) * 0.5f, 0.f), 1.f);
        const float ly = fminf(fmaxf(rp.y + tanhf(ol.y) * 0.5f, 0.f), 1.f);
        const float x = lx * (float)IMG - 0.5f;
        const float y = ly * (float)IMG - 0.5f;
        const float x0f = floorf(x), y0f = floorf(y);
        const int x0 = (int)x0f, y0 = (int)y0f;
        const float wx1 = x - x0f, wx0 = 1.f - wx1;
        const float wy1 = y - y0f, wy0 = 1.f - wy1;
        const bool vx0 = (x0 >= 0), vx1 = (x0 + 1 < IMG);
        const bool vy0 = (y0 >= 0), vy1 = (y0 + 1 < IMG);
        float4 w;
        w.x = (vx0 && vy0) ? wx0 * wy0 * aw : 0.f;
        w.y = (vx1 && vy0) ? wx1 * wy0 * aw : 0.f;
        w.z = (vx0 && vy1) ? wx0 * wy1 * aw : 0.f;
        w.w = (vx1 && vy1) ? wx1 * wy1 * aw : 0.f;
        const int x0c = min(max(x0, 0), IMG - 1), x1c = min(max(x0 + 1, 0), IMG - 1);
        const int y0c = min(max(y0, 0), IMG - 1), y1c = min(max(y0 + 1, 0), IMG - 1);
        s_w[sub][q] = w;
        s_xy[sub][q] = (unsigned)x0c | ((unsigned)x1c << 8) | ((unsigned)y0c << 16) | ((unsigned)y1c << 24);
    }
    __syncthreads();

    const int sub = t >> 7;
    const int tt = t & 127;
    const int h = tt >> 4;
    const int dp = (tt & 15) * 2;
    const int bn = bn0 + sub;
    const int b = bn >> 12;
    const unsigned short* base = projv + ((size_t)b << 20) + h * HDIM + dp;

    float a0 = 0.f, a1 = 0.f;
    #pragma unroll
    for (int p = 0; p < 4; ++p) {
        const float4 w = s_w[sub][h * 4 + p];
        const unsigned xy = s_xy[sub][h * 4 + p];
        const int x0 = xy & 255, x1 = (xy >> 8) & 255, y0 = (xy >> 16) & 255, y1 = xy >> 24;
        const unsigned v00 = *(const unsigned*)&base[((y0 << 6) + x0) << 8];
        const unsigned v01 = *(const unsigned*)&base[((y0 << 6) + x1) << 8];
        const unsigned v10 = *(const unsigned*)&base[((y1 << 6) + x0) << 8];
        const unsigned v11 = *(const unsigned*)&base[((y1 << 6) + x1) << 8];
        a0 += w.x * b2f((unsigned short)(v00 & 0xffff))
            + w.y * b2f((unsigned short)(v01 & 0xffff))
            + w.z * b2f((unsigned short)(v10 & 0xffff))
            + w.w * b2f((unsigned short)(v11 & 0xffff));
        a1 += w.x * b2f((unsigned short)(v00 >> 16))
            + w.y * b2f((unsigned short)(v01 >> 16))
            + w.z * b2f((unsigned short)(v10 >> 16))
            + w.w * b2f((unsigned short)(v11 >> 16));
    }
    const unsigned outp = (unsigned)f2b(a0) | ((unsigned)f2b(a1) << 16);
    *(unsigned*)&sampled[(size_t)bn * 256 + h * HDIM + dp] = outp;
}

// ---------------------------------------------------------------------------
extern "C" void kernel_launch(void* const* d_in, const int* in_sizes, int n_in,
                              void* d_out, int out_size, void* d_ws, size_t ws_size,
                              hipStream_t stream)
{
    const float* query  = (const float*)d_in[0];
    const float* value  = (const float*)d_in[1];
    const float* refp   = (const float*)d_in[2];
    const float* W_off  = (const float*)d_in[3];
    const float* b_off  = (const float*)d_in[4];
    const float* W_attn = (const float*)d_in[5];
    const float* b_attn = (const float*)d_in[6];
    const float* W_val  = (const float*)d_in[7];
    const float* b_val  = (const float*)d_in[8];
    const float* W_out  = (const float*)d_in[9];
    const float* b_out  = (const float*)d_in[10];
    float* out = (float*)d_out;

    // workspace layout
    char* ws = (char*)d_ws;
    unsigned short* value_bf = (unsigned short*)ws; ws += (size_t)MTOT * 256 * 2;
    unsigned short* projv    = (unsigned short*)ws; ws += (size_t)MTOT * 256 * 2;
    unsigned short* sampled  = (unsigned short*)ws; ws += (size_t)MTOT * 256 * 2;
    float*          lin      = (float*)ws;          ws += (size_t)MTOT * 96 * 4;
    unsigned short* Wv_t     = (unsigned short*)ws; ws += 256 * 256 * 2;
    unsigned short* Wo_t     = (unsigned short*)ws; ws += 256 * 256 * 2;
    float*          Wboth    = (float*)ws;          ws += 256 * 96 * 4;
    float*          biasboth = (float*)ws;          ws += 128 * 4;

    dim3 blk(256);

    // 1) conversions
    cvt_value_kernel<<<dim3(MTOT * 256 / 8 / 256), blk, 0, stream>>>(value, value_bf, MTOT * 256 / 8);
    cvt_weights_kernel<<<dim3(256), blk, 0, stream>>>(W_val, W_out, W_off, W_attn, b_off, b_attn,
                                                      Wv_t, Wo_t, Wboth, biasboth);

    // 2) offset+attn logits (f32): lin = query @ Wboth + biasboth   [M x 96]
    gemm_bias_kernel<64, 64, 16><<<dim3(MTOT / 64, 2), blk, 0, stream>>>(
        query, CDIM, Wboth, 96, biasboth, lin, 96, 96, CDIM);

    // 3) value projection (bf16 MFMA): projv = value @ W_val + b_val  -> bf16
    gemm_bf16_kernel<true><<<dim3(MTOT / 128, 2), blk, 0, stream>>>(value_bf, Wv_t, b_val, projv);

    // 4) fused offsets/softmax/bilinear gather -> sampled (bf16)
    sample_gather_kernel<<<dim3(MTOT / 2), blk, 0, stream>>>(projv, lin, refp, sampled);

    // 5) output projection (bf16 MFMA): out = sampled @ W_out + b_out -> f32
    gemm_bf16_kernel<false><<<dim3(MTOT / 128, 2), blk, 0, stream>>>(sampled, Wo_t, b_out, out);
}

// Round 3
// 89.561 us; speedup vs baseline: 3.2053x; 1.1597x over previous
//
#include <hip/hip_runtime.h>
#include <math.h>

#define NHEAD 8
#define NPT 4
#define HDIM 32
#define IMG 64      // H = W = 64
#define CDIM 256
#define NQ 4096
#define BATCH 8
#define MTOT (BATCH * NQ)   // 32768

typedef __attribute__((ext_vector_type(8))) short bf16x8;
typedef __attribute__((ext_vector_type(4))) float f32x4;

__device__ __forceinline__ unsigned short f2b(float f) {
    union { float f; unsigned u; } v; v.f = f;
    unsigned r = (v.u + 0x7FFFu + ((v.u >> 16) & 1u)) >> 16;
    return (unsigned short)r;
}
__device__ __forceinline__ float b2f(unsigned short u) {
    union { unsigned u; float f; } v; v.u = ((unsigned)u) << 16;
    return v.f;
}

// XOR swizzle: spreads rows across banks for ds_read_b128 column-slice reads.
// col in ushort units, multiple of 8 preserved (16B-aligned accesses stay aligned).
#define SWZ(row, col) ((col) ^ (((row) & 7) << 3))

// ---------------------------------------------------------------------------
// Weight prep:
//  - Wv_t / Wo_t: [n][k] bf16 transposed copies of W_val / W_out
//  - Wl_h / Wl_l: [128][256] bf16 hi/lo split of packed [W_off | W_attn | 0pad]
//  - bias_lin[128]: b_off | b_attn | 0
// ---------------------------------------------------------------------------
__global__ __launch_bounds__(256)
void cvt_weights_kernel(const float* __restrict__ Wv, const float* __restrict__ Wo,
                        const float* __restrict__ Woff, const float* __restrict__ Wattn,
                        const float* __restrict__ boff, const float* __restrict__ battn,
                        unsigned short* __restrict__ Wv_t, unsigned short* __restrict__ Wo_t,
                        unsigned short* __restrict__ Wl_h, unsigned short* __restrict__ Wl_l,
                        float* __restrict__ bias_lin)
{
    int tid = blockIdx.x * 256 + threadIdx.x;   // 0 .. 65535
    int n = tid & 255, k = tid >> 8;
    Wv_t[n * 256 + k] = f2b(Wv[k * 256 + n]);
    Wo_t[n * 256 + k] = f2b(Wo[k * 256 + n]);
    if (tid < 128 * 256) {
        int nn = tid >> 8;       // output col 0..127
        int kk = tid & 255;
        float v = (nn < 64) ? Woff[kk * 64 + nn]
                : (nn < 96) ? Wattn[kk * 32 + (nn - 64)] : 0.f;
        unsigned short hi = f2b(v);
        unsigned short lo = f2b(v - b2f(hi));
        Wl_h[nn * 256 + kk] = hi;
        Wl_l[nn * 256 + kk] = lo;
    }
    if (tid < 128)
        bias_lin[tid] = (tid < 64) ? boff[tid] : (tid < 96) ? battn[tid - 64] : 0.f;
}

// ---------------------------------------------------------------------------
// Split-precision MFMA GEMM for offset/attn logits:
//   lin[M x 96] = query(f32) @ [W_off|W_attn] + bias   via 3-term bf16 split
// Tile 128 rows x 128 cols (cols 96..127 zero-padded), K=256, BK=64, 4 waves.
// ---------------------------------------------------------------------------
__global__ __launch_bounds__(256)
void lin_gemm_kernel(const float* __restrict__ Q,
                     const unsigned short* __restrict__ Wl_h,
                     const unsigned short* __restrict__ Wl_l,
                     const float* __restrict__ bias,
                     float* __restrict__ lin)
{
    __shared__ unsigned short Ah[128][64], Al[128][64];
    __shared__ unsigned short Bh[128][64], Bl[128][64];

    const int tid  = threadIdx.x;
    const int lane = tid & 63;
    const int wid  = tid >> 6;
    const int gm = blockIdx.x * 128;
    const int wr = (wid >> 1) * 64;
    const int wc = (wid & 1) * 64;
    const int l15 = lane & 15;
    const int lk  = (lane >> 4) * 8;

    f32x4 acc[4][4];
    #pragma unroll
    for (int m = 0; m < 4; ++m)
        #pragma unroll
        for (int n = 0; n < 4; ++n)
            #pragma unroll
            for (int r = 0; r < 4; ++r) acc[m][n][r] = 0.f;

    for (int k0 = 0; k0 < 256; k0 += 64) {
        #pragma unroll
        for (int it = 0; it < 4; ++it) {
            const int chunk = it * 256 + tid;
            const int row = chunk >> 3;
            const int kc  = (chunk & 7) << 3;
            const float4* src = (const float4*)&Q[(size_t)(gm + row) * 256 + k0 + kc];
            const float4 a = src[0], b = src[1];
            float f[8] = {a.x, a.y, a.z, a.w, b.x, b.y, b.z, b.w};
            unsigned short h[8], l[8];
            #pragma unroll
            for (int j = 0; j < 8; ++j) {
                h[j] = f2b(f[j]);
                l[j] = f2b(f[j] - b2f(h[j]));
            }
            const int sc = SWZ(row, kc);
            *(uint4*)&Ah[row][sc] = *(const uint4*)h;
            *(uint4*)&Al[row][sc] = *(const uint4*)l;
            *(uint4*)&Bh[row][sc] = *(const uint4*)&Wl_h[(size_t)row * 256 + k0 + kc];
            *(uint4*)&Bl[row][sc] = *(const uint4*)&Wl_l[(size_t)row * 256 + k0 + kc];
        }
        __syncthreads();

        #pragma unroll
        for (int kk = 0; kk < 64; kk += 32) {
            bf16x8 ah[4], al[4], bh[4], bl[4];
            #pragma unroll
            for (int m = 0; m < 4; ++m) {
                const int r = wr + m * 16 + l15;
                const int c = SWZ(r, kk + lk);
                ah[m] = *(const bf16x8*)&Ah[r][c];
                al[m] = *(const bf16x8*)&Al[r][c];
            }
            #pragma unroll
            for (int n = 0; n < 4; ++n) {
                const int r = wc + n * 16 + l15;
                const int c = SWZ(r, kk + lk);
                bh[n] = *(const bf16x8*)&Bh[r][c];
                bl[n] = *(const bf16x8*)&Bl[r][c];
            }
            #pragma unroll
            for (int m = 0; m < 4; ++m)
                #pragma unroll
                for (int n = 0; n < 4; ++n) {
                    acc[m][n] = __builtin_amdgcn_mfma_f32_16x16x32_bf16(ah[m], bh[n], acc[m][n], 0, 0, 0);
                    acc[m][n] = __builtin_amdgcn_mfma_f32_16x16x32_bf16(ah[m], bl[n], acc[m][n], 0, 0, 0);
                    acc[m][n] = __builtin_amdgcn_mfma_f32_16x16x32_bf16(al[m], bh[n], acc[m][n], 0, 0, 0);
                }
        }
        __syncthreads();
    }

    const int cr = (lane >> 4) * 4;
    #pragma unroll
    for (int n = 0; n < 4; ++n) {
        const int col = wc + n * 16 + l15;
        if (col < 96) {
            const float bv = bias[col];
            #pragma unroll
            for (int m = 0; m < 4; ++m)
                #pragma unroll
                for (int r = 0; r < 4; ++r) {
                    const int row = gm + wr + m * 16 + cr + r;
                    lin[(size_t)row * 96 + col] = acc[m][n][r] + bv;
                }
        }
    }
}

// ---------------------------------------------------------------------------
// bf16 MFMA GEMM: C[M x 256] = A[M x 256] @ Bt^T + bias
// A_F32: A is f32, converted to bf16 during LDS staging (fused cvt).
// ---------------------------------------------------------------------------
template<bool A_F32, bool OUT_BF16>
__global__ __launch_bounds__(256)
void gemm_bf16_kernel(const void* __restrict__ Ap,
                      const unsigned short* __restrict__ Bt,
                      const float* __restrict__ bias,
                      void* __restrict__ C)
{
    __shared__ unsigned short As[128][64];
    __shared__ unsigned short Bs[128][64];

    const int tid  = threadIdx.x;
    const int lane = tid & 63;
    const int wid  = tid >> 6;
    const int gm = blockIdx.x * 128;
    const int gn = blockIdx.y * 128;
    const int wr = (wid >> 1) * 64;
    const int wc = (wid & 1) * 64;
    const int l15 = lane & 15;
    const int lk  = (lane >> 4) * 8;

    f32x4 acc[4][4];
    #pragma unroll
    for (int m = 0; m < 4; ++m)
        #pragma unroll
        for (int n = 0; n < 4; ++n)
            #pragma unroll
            for (int r = 0; r < 4; ++r) acc[m][n][r] = 0.f;

    for (int k0 = 0; k0 < 256; k0 += 64) {
        #pragma unroll
        for (int it = 0; it < 4; ++it) {
            const int chunk = it * 256 + tid;
            const int row = chunk >> 3;
            const int kc  = (chunk & 7) << 3;
            const int sc = SWZ(row, kc);
            if (A_F32) {
                const float4* src = (const float4*)&((const float*)Ap)[(size_t)(gm + row) * 256 + k0 + kc];
                const float4 a = src[0], b = src[1];
                float f[8] = {a.x, a.y, a.z, a.w, b.x, b.y, b.z, b.w};
                unsigned short h[8];
                #pragma unroll
                for (int j = 0; j < 8; ++j) h[j] = f2b(f[j]);
                *(uint4*)&As[row][sc] = *(const uint4*)h;
            } else {
                *(uint4*)&As[row][sc] =
                    *(const uint4*)&((const unsigned short*)Ap)[(size_t)(gm + row) * 256 + k0 + kc];
            }
            *(uint4*)&Bs[row][sc] = *(const uint4*)&Bt[(size_t)(gn + row) * 256 + k0 + kc];
        }
        __syncthreads();

        #pragma unroll
        for (int kk = 0; kk < 64; kk += 32) {
            bf16x8 a[4], b[4];
            #pragma unroll
            for (int m = 0; m < 4; ++m) {
                const int r = wr + m * 16 + l15;
                a[m] = *(const bf16x8*)&As[r][SWZ(r, kk + lk)];
            }
            #pragma unroll
            for (int n = 0; n < 4; ++n) {
                const int r = wc + n * 16 + l15;
                b[n] = *(const bf16x8*)&Bs[r][SWZ(r, kk + lk)];
            }
            #pragma unroll
            for (int m = 0; m < 4; ++m)
                #pragma unroll
                for (int n = 0; n < 4; ++n)
                    acc[m][n] = __builtin_amdgcn_mfma_f32_16x16x32_bf16(a[m], b[n], acc[m][n], 0, 0, 0);
        }
        __syncthreads();
    }

    const int cr = (lane >> 4) * 4;
    #pragma unroll
    for (int n = 0; n < 4; ++n) {
        const int col = gn + wc + n * 16 + l15;
        const float bv = bias[col];
        #pragma unroll
        for (int m = 0; m < 4; ++m) {
            #pragma unroll
            for (int r = 0; r < 4; ++r) {
                const int row = gm + wr + m * 16 + cr + r;
                const float v = acc[m][n][r] + bv;
                if (OUT_BF16)
                    ((unsigned short*)C)[(size_t)row * 256 + col] = f2b(v);
                else
                    ((float*)C)[(size_t)row * 256 + col] = v;
            }
        }
    }
}

// ---------------------------------------------------------------------------
// Fused sampling: block handles 2 queries; 64 lanes compute weights/coords,
// then 256 threads gather bf16 corners (2 channels each).
// ---------------------------------------------------------------------------
__global__ __launch_bounds__(256)
void sample_gather_kernel(const unsigned short* __restrict__ projv, // [B][4096][256] bf16
                          const float* __restrict__ lin,            // [M][96]
                          const float* __restrict__ refp,           // [M][2]
                          unsigned short* __restrict__ sampled)     // [M][256] bf16
{
    __shared__ float4 s_w[2][32];
    __shared__ unsigned s_xy[2][32];

    const int t = threadIdx.x;
    const int bn0 = blockIdx.x * 2;

    if (t < 64) {
        const int sub = t >> 5;
        const int q = t & 31;          // h*4 + p
        const int h = q >> 2;
        const int p = q & 3;
        const int bn = bn0 + sub;
        const float2 rp = *(const float2*)&refp[(size_t)bn * 2];
        const float2 ol = *(const float2*)&lin[(size_t)bn * 96 + h * 8 + p * 2];
        const float al  = lin[(size_t)bn * 96 + 64 + q];

        float mx = al;
        mx = fmaxf(mx, __shfl_xor(mx, 1));
        mx = fmaxf(mx, __shfl_xor(mx, 2));
        float e = expf(al - mx);
        float s = e;
        s += __shfl_xor(s, 1);
        s += __shfl_xor(s, 2);
        const float aw = e / s;

        const float lx = fminf(fmaxf(rp.x + tanhf(ol.x) * 0.5f, 0.f), 1.f);
        const float ly = fminf(fmaxf(rp.y + tanhf(ol.y) * 0.5f, 0.f), 1.f);
        const float x = lx * (float)IMG - 0.5f;
        const float y = ly * (float)IMG - 0.5f;
        const float x0f = floorf(x), y0f = floorf(y);
        const int x0 = (int)x0f, y0 = (int)y0f;
        const float wx1 = x - x0f, wx0 = 1.f - wx1;
        const float wy1 = y - y0f, wy0 = 1.f - wy1;
        const bool vx0 = (x0 >= 0), vx1 = (x0 + 1 < IMG);
        const bool vy0 = (y0 >= 0), vy1 = (y0 + 1 < IMG);
        float4 w;
        w.x = (vx0 && vy0) ? wx0 * wy0 * aw : 0.f;
        w.y = (vx1 && vy0) ? wx1 * wy0 * aw : 0.f;
        w.z = (vx0 && vy1) ? wx0 * wy1 * aw : 0.f;
        w.w = (vx1 && vy1) ? wx1 * wy1 * aw : 0.f;
        const int x0c = min(max(x0, 0), IMG - 1), x1c = min(max(x0 + 1, 0), IMG - 1);
        const int y0c = min(max(y0, 0), IMG - 1), y1c = min(max(y0 + 1, 0), IMG - 1);
        s_w[sub][q] = w;
        s_xy[sub][q] = (unsigned)x0c | ((unsigned)x1c << 8) | ((unsigned)y0c << 16) | ((unsigned)y1c << 24);
    }
    __syncthreads();

    const int sub = t >> 7;
    const int tt = t & 127;
    const int h = tt >> 4;
    const int dp = (tt & 15) * 2;
    const int bn = bn0 + sub;
    const int b = bn >> 12;
    const unsigned short* base = projv + ((size_t)b << 20) + h * HDIM + dp;

    float a0 = 0.f, a1 = 0.f;
    #pragma unroll
    for (int p = 0; p < 4; ++p) {
        const float4 w = s_w[sub][h * 4 + p];
        const unsigned xy = s_xy[sub][h * 4 + p];
        const int x0 = xy & 255, x1 = (xy >> 8) & 255, y0 = (xy >> 16) & 255, y1 = xy >> 24;
        const unsigned v00 = *(const unsigned*)&base[((y0 << 6) + x0) << 8];
        const unsigned v01 = *(const unsigned*)&base[((y0 << 6) + x1) << 8];
        const unsigned v10 = *(const unsigned*)&base[((y1 << 6) + x0) << 8];
        const unsigned v11 = *(const unsigned*)&base[((y1 << 6) + x1) << 8];
        a0 += w.x * b2f((unsigned short)(v00 & 0xffff))
            + w.y * b2f((unsigned short)(v01 & 0xffff))
            + w.z * b2f((unsigned short)(v10 & 0xffff))
            + w.w * b2f((unsigned short)(v11 & 0xffff));
        a1 += w.x * b2f((unsigned short)(v00 >> 16))
            + w.y * b2f((unsigned short)(v01 >> 16))
            + w.z * b2f((unsigned short)(v10 >> 16))
            + w.w * b2f((unsigned short)(v11 >> 16));
    }
    const unsigned outp = (unsigned)f2b(a0) | ((unsigned)f2b(a1) << 16);
    *(unsigned*)&sampled[(size_t)bn * 256 + h * HDIM + dp] = outp;
}

// ---------------------------------------------------------------------------
extern "C" void kernel_launch(void* const* d_in, const int* in_sizes, int n_in,
                              void* d_out, int out_size, void* d_ws, size_t ws_size,
                              hipStream_t stream)
{
    const float* query  = (const float*)d_in[0];
    const float* value  = (const float*)d_in[1];
    const float* refp   = (const float*)d_in[2];
    const float* W_off  = (const float*)d_in[3];
    const float* b_off  = (const float*)d_in[4];
    const float* W_attn = (const float*)d_in[5];
    const float* b_attn = (const float*)d_in[6];
    const float* W_val  = (const float*)d_in[7];
    const float* b_val  = (const float*)d_in[8];
    const float* W_out  = (const float*)d_in[9];
    const float* b_out  = (const float*)d_in[10];
    float* out = (float*)d_out;

    // workspace layout
    char* ws = (char*)d_ws;
    unsigned short* projv    = (unsigned short*)ws; ws += (size_t)MTOT * 256 * 2;
    unsigned short* sampled  = (unsigned short*)ws; ws += (size_t)MTOT * 256 * 2;
    float*          lin      = (float*)ws;          ws += (size_t)MTOT * 96 * 4;
    unsigned short* Wv_t     = (unsigned short*)ws; ws += 256 * 256 * 2;
    unsigned short* Wo_t     = (unsigned short*)ws; ws += 256 * 256 * 2;
    unsigned short* Wl_h     = (unsigned short*)ws; ws += 128 * 256 * 2;
    unsigned short* Wl_l     = (unsigned short*)ws; ws += 128 * 256 * 2;
    float*          bias_lin = (float*)ws;          ws += 128 * 4;

    dim3 blk(256);

    // 1) weight prep
    cvt_weights_kernel<<<dim3(256), blk, 0, stream>>>(W_val, W_out, W_off, W_attn, b_off, b_attn,
                                                      Wv_t, Wo_t, Wl_h, Wl_l, bias_lin);

    // 2) offset+attn logits via split-precision MFMA: lin = query @ [W_off|W_attn] + b
    lin_gemm_kernel<<<dim3(MTOT / 128), blk, 0, stream>>>(query, Wl_h, Wl_l, bias_lin, lin);

    // 3) value projection (fused f32->bf16 A-staging): projv = value @ W_val + b_val -> bf16
    gemm_bf16_kernel<true, true><<<dim3(MTOT / 128, 2), blk, 0, stream>>>(value, Wv_t, b_val, projv);

    // 4) fused offsets/softmax/bilinear gather -> sampled (bf16)
    sample_gather_kernel<<<dim3(MTOT / 2), blk, 0, stream>>>(projv, lin, refp, sampled);

    // 5) output projection: out = sampled @ W_out + b_out -> f32
    gemm_bf16_kernel<false, false><<<dim3(MTOT / 128, 2), blk, 0, stream>>>(sampled, Wo_t, b_out, out);
}